// Round 10
// baseline (1229.730 us; speedup 1.0000x reference)
//
#include <hip/hip_runtime.h>

// PointNet++ SA module on MI355X.
// Pipeline: fused{cvt, pk, FPS} ; ball query ; fused MLP+max.
// Layer1 trick: x_j@W1a precomputed per point (16x reuse); pair-wise part is only rel@W1b.
// Layers 2/3 use v_mfma_f32_16x16x32_f16 (no fp32 MFMA on CDNA4).
// R2/R4: FPS: 4 waves (1/SIMD), DPP f32 max reduce; argmax via ballot+ctz+readlane. PROVEN.
// R8: fuse {fps | pk | cvt} on disjoint blockIdx ranges: 986 -> 860us, front 585us.
// R9: (a) packed f32x2 sub/mul/add + scalar min/max: front 585->531. PROVEN.
//     (b) 1-wave ballq REGRESSED (+29us tail): workgroup-slot cap halves occupancy.
// R10: (1) ballq: 4-wave blocks, ZERO barriers — each wave sorts its OWN list; a wave's
//      DS ops are one in-order instruction stream, so intra-wave cross-lane LDS needs
//      no s_barrier. (2) fps: 2 clouds per block (4 blocks), superstep interleave —
//      cloud B's issue hides cloud A's serial latencies (centroid read, DPP, merge),
//      one barrier serves both clouds. Dynamic LDS 106,624 B.

#define NB 8
#define NP 4096
#define MP 1024
#define NC 8192         // NB*MP centroids
#define CIN 64
#define D1 128
#define D2 128
#define D3 256
#define CAP 512         // ball-query candidate capacity (E[count]~137, 32 sigma safe)

static constexpr float R2F = 0.04f;   // (0.2)^2 in f32, bit-identical to jnp promotion

typedef _Float16 f16;
typedef _Float16 half8 __attribute__((ext_vector_type(8)));
typedef float floatx4 __attribute__((ext_vector_type(4)));
typedef float f32x2 __attribute__((ext_vector_type(2)));
typedef unsigned long long u64;

// d_out layout (floats): [NC*256 out][NC*3 pos_out][NC batch_out]
#define OUT1 ((size_t)NC * D3)
#define OUT2 (OUT1 + (size_t)NC * 3)

// ---------------- fused front end: blocks 0-3 FPS(x2 clouds), 4-1027 pk, 1028-1091 cvt
template<int CTRL>
__device__ __forceinline__ float dppmax(float v) {
  const int iv = __builtin_bit_cast(int, v);
  const int sh = __builtin_amdgcn_update_dpp(iv, iv, CTRL, 0xf, 0xf, false);
  return fmaxf(v, __builtin_bit_cast(float, sh));
}

struct FpsS2 {
  u64 pkey[2][2][4];        //   128 B: [buf][cloud][wave]
  int cidx[2][MP];          //  8192 B: winner logs
  float ldspos[2][NP * 3];  // 98304 B: both clouds resident
};                          // total 106,624 B (dynamic LDS)
struct PkS { float wl[CIN * D1]; float xl[32 * CIN]; };   // 40960 B

__launch_bounds__(256)
__global__ void front_kernel(const float* __restrict__ pos, const float* __restrict__ x,
                             const float* __restrict__ W1, const float* __restrict__ b1,
                             const float* __restrict__ W2, const float* __restrict__ W3,
                             float* __restrict__ qpos, f16* __restrict__ P,
                             f16* __restrict__ W2t, f16* __restrict__ W3t,
                             float* __restrict__ W1b, float* __restrict__ dout) {
  #pragma clang fp contract(off)
  extern __shared__ __align__(16) char raw[];
  const int bid = blockIdx.x;
  const int t = threadIdx.x;

  if (bid < NB / 2) {
    // ============ FPS: 1 block (4 waves, 1/SIMD) handles clouds 2bid, 2bid+1 ==========
    FpsS2& S = *reinterpret_cast<FpsS2*>(raw);
    const int lane = t & 63, wv = t >> 6;
    for (int cl = 0; cl < 2; ++cl)
      for (int e = t; e < NP * 3; e += 256)
        S.ldspos[cl][e] = pos[(size_t)(bid * 2 + cl) * NP * 3 + e];
    __syncthreads();
    // blocked mapping: thread t owns points [t*16, t*16+16) of each cloud
    // coords packed f32x2 (v_pk_add/mul_f32); d scalar (no v_pk_min/max on gfx950)
    f32x2 px[2][8], py[2][8], pz[2][8];
    float d[2][16];
    #pragma unroll
    for (int cl = 0; cl < 2; ++cl)
      #pragma unroll
      for (int i = 0; i < 8; ++i) {
        const int p = t * 16 + 2 * i;
        px[cl][i] = (f32x2){S.ldspos[cl][p * 3 + 0], S.ldspos[cl][p * 3 + 3]};
        py[cl][i] = (f32x2){S.ldspos[cl][p * 3 + 1], S.ldspos[cl][p * 3 + 4]};
        pz[cl][i] = (f32x2){S.ldspos[cl][p * 3 + 2], S.ldspos[cl][p * 3 + 5]};
        d[cl][2 * i] = INFINITY; d[cl][2 * i + 1] = INFINITY;
      }
    int g[2] = {0, 0};
    for (int step = 0; step < MP; ++step) {
      if (t == 0) { S.cidx[0][step] = g[0]; S.cidx[1][step] = g[1]; }
      #pragma unroll
      for (int cl = 0; cl < 2; ++cl) {
        const float cx = S.ldspos[cl][g[cl] * 3 + 0];
        const float cy = S.ldspos[cl][g[cl] * 3 + 1];
        const float cz = S.ldspos[cl][g[cl] * 3 + 2];
        const f32x2 cx2 = cx, cy2 = cy, cz2 = cz;
        // packed sub/mul/add (contract off -> separate rn ops, exact JAX order)
        float lv = -1.0f;
        #pragma unroll
        for (int i = 0; i < 8; ++i) {
          const f32x2 dx = px[cl][i] - cx2;
          const f32x2 dy = py[cl][i] - cy2;
          const f32x2 dz = pz[cl][i] - cz2;
          const f32x2 nd = (dx * dx + dy * dy) + dz * dz;
          d[cl][2 * i]     = fminf(d[cl][2 * i],     nd.x);
          d[cl][2 * i + 1] = fminf(d[cl][2 * i + 1], nd.y);
          lv = fmaxf(lv, d[cl][2 * i]);
          lv = fmaxf(lv, d[cl][2 * i + 1]);
        }
        // lane-local argmax, lowest-i tie-break (descending overwrite)
        int li = 15;
        #pragma unroll
        for (int i = 14; i >= 0; --i) li = (d[cl][i] == lv) ? i : li;
        // in-wave max via DPP (VALU pipe): result in lane 63
        float wm = lv;
        wm = dppmax<0xB1>(wm);    // quad_perm [1,0,3,2]
        wm = dppmax<0x4E>(wm);    // quad_perm [2,3,0,1]
        wm = dppmax<0x141>(wm);   // row_half_mirror
        wm = dppmax<0x140>(wm);   // row_mirror
        wm = dppmax<0x142>(wm);   // row_bcast:15
        wm = dppmax<0x143>(wm);   // row_bcast:31
        const float M = __builtin_bit_cast(float,
            __builtin_amdgcn_readlane(__builtin_bit_cast(int, wm), 63));
        // wave argmax: lowest lane holding M, then its lowest i
        const u64 bal = __ballot(lv == M);
        const int Ls = (int)__builtin_ctzll(bal);
        const int sli = __builtin_amdgcn_readlane(li, Ls);
        const int gw = ((wv << 6) + Ls) * 16 + sli;   // wave winner global idx
        if (lane == 0)
          S.pkey[step & 1][cl][wv] = ((u64)__float_as_uint(M) << 32) | (unsigned int)~gw;
      }
      __syncthreads();
      // cross-wave merge for both clouds (redundant in every thread)
      #pragma unroll
      for (int cl = 0; cl < 2; ++cl) {
        u64 best = S.pkey[step & 1][cl][0];
        #pragma unroll
        for (int w = 1; w < 4; ++w) {
          const u64 o = S.pkey[step & 1][cl][w];
          best = o > best ? o : best;
        }
        g[cl] = (int)~(unsigned int)best;
      }
    }
    __syncthreads();
    // epilogue: flush both clouds' centroid outputs in parallel
    for (int s = t; s < 2 * MP; s += 256) {
      const int cl = s >> 10, ss = s & (MP - 1);
      const int b = bid * 2 + cl;
      const int ci = (b << 10) + ss;
      const int p = S.cidx[cl][ss];
      const float cx = S.ldspos[cl][p * 3 + 0];
      const float cy = S.ldspos[cl][p * 3 + 1];
      const float cz = S.ldspos[cl][p * 3 + 2];
      qpos[ci * 3 + 0] = cx; qpos[ci * 3 + 1] = cy; qpos[ci * 3 + 2] = cz;
      dout[OUT1 + (size_t)ci * 3 + 0] = cx;
      dout[OUT1 + (size_t)ci * 3 + 1] = cy;
      dout[OUT1 + (size_t)ci * 3 + 2] = cz;
      dout[OUT2 + ci] = (float)b;
    }
  } else if (bid < NB / 2 + 1024) {
    // ================= pk: P = x @ W1[0:64] + b1 (fp16 out), 32 rows/block ==========
    PkS& S = *reinterpret_cast<PkS*>(raw);
    const int r0 = (bid - NB / 2) * 32;
    for (int e = t; e < CIN * D1; e += 256) S.wl[e] = W1[e];
    for (int e = t; e < 32 * CIN; e += 256)
      S.xl[e] = x[(size_t)(r0 + (e >> 6)) * CIN + (e & 63)];
    __syncthreads();
    const int c = t & 127;
    const int rh = t >> 7;           // wave-uniform (waves 0,1 -> 0; waves 2,3 -> 1)
    const float bc = b1[c];
    for (int rr = 0; rr < 32; rr += 2) {
      const int r = rr + rh;
      float acc = bc;
      #pragma unroll
      for (int k = 0; k < CIN; ++k) acc = __fmaf_rn(S.xl[r * CIN + k], S.wl[k * D1 + c], acc);
      P[(size_t)(r0 + r) * D1 + c] = (f16)acc;
    }
  } else {
    // ================= cvt: weight transpose -> fp16 (64 blocks, grid-stride) ========
    const int stride = 64 * 256;
    const int i = (bid - (NB / 2 + 1024)) * 256 + t;
    for (int e = i; e < D1 * D2; e += stride) {      // W2t[c][k] = W2[k][c]
      int c = e >> 7, k = e & 127;
      W2t[c * 128 + k] = (f16)W2[k * D2 + c];
    }
    for (int e = i; e < D2 * D3; e += stride) {      // W3t[c][k] = W3[k][c]
      int c = e >> 7, k = e & 127;
      W3t[c * 128 + k] = (f16)W3[k * D3 + c];
    }
    for (int e = i; e < 3 * D1; e += stride) W1b[e] = W1[64 * D1 + e];  // rel rows of W1
  }
}

// ------- ball query: 4 waves/block, each wave owns one centroid; ZERO barriers -------
// (a wave's DS ops are one in-order instruction stream -> intra-wave cross-lane LDS
//  communication needs no s_barrier; waves touch disjoint list[wv] regions)
__launch_bounds__(256)
__global__ void ballq_kernel(const float* __restrict__ pos, const float* __restrict__ qpos,
                             int* __restrict__ nbr) {
  __shared__ unsigned long long list[4][CAP];   // 16KB
  const int t = threadIdx.x;
  const int wv = t >> 6, lane = t & 63;
  const int ci = blockIdx.x * 4 + wv;
  const int b = ci >> 10;
  const int base = b * NP;
  const float qx = qpos[ci * 3 + 0], qy = qpos[ci * 3 + 1], qz = qpos[ci * 3 + 2];
  int cnt = 0;
  for (int chunk = 0; chunk < NP / 64; ++chunk) {
    const int p = chunk * 64 + lane;
    const float x = pos[(size_t)(base + p) * 3 + 0];
    const float y = pos[(size_t)(base + p) * 3 + 1];
    const float z = pos[(size_t)(base + p) * 3 + 2];
    const float dx = __fsub_rn(qx, x), dy = __fsub_rn(qy, y), dz = __fsub_rn(qz, z);
    const float d2 = __fadd_rn(__fadd_rn(__fmul_rn(dx, dx), __fmul_rn(dy, dy)),
                               __fmul_rn(dz, dz));
    const bool in = d2 <= R2F;
    const unsigned long long mask = __ballot(in);
    if (in) {
      const int slot = cnt + __popcll(mask & ((1ull << lane) - 1ull));
      if (slot < CAP)
        list[wv][slot] = ((unsigned long long)__float_as_uint(d2) << 32) | (unsigned int)p;
    }
    cnt += __popcll(mask);
  }
  const int cntc = cnt < CAP ? cnt : CAP;
  for (int s = cntc + lane; s < CAP; s += 64) list[wv][s] = ~0ull;
  // bitonic ascending sort of (d2_bits, idx) -> exact top_k tie-break (lowest idx)
  for (int ks = 2; ks <= CAP; ks <<= 1) {
    for (int jj = ks >> 1; jj > 0; jj >>= 1) {
      for (int i = lane; i < CAP; i += 64) {
        const int partner = i ^ jj;
        if (partner > i) {
          const bool up = ((i & ks) == 0);
          const unsigned long long a = list[wv][i], c = list[wv][partner];
          if (up ? (a > c) : (a < c)) { list[wv][i] = c; list[wv][partner] = a; }
        }
      }
    }
  }
  const unsigned long long e = list[wv][lane];
  const int idx = (int)(e & 0xFFFFFFFFull);
  nbr[(ci << 6) + lane] = (lane < cntc) ? idx : -1;
}

// ---------------- fused MLP + max aggregation: 1 block (4 waves) per centroid ----------------
__launch_bounds__(256)
__global__ void mlp_kernel(const float* __restrict__ pos, const float* __restrict__ qpos,
                           const int* __restrict__ nbr, const f16* __restrict__ P,
                           const float* __restrict__ W1b, const f16* __restrict__ W2t,
                           const float* __restrict__ b2c, const f16* __restrict__ W3t,
                           const float* __restrict__ b3c, float* __restrict__ out) {
  __shared__ f16 h1s[64 * 128];   // 16KB, element (r,k) at r*128 + (k ^ ((r&7)<<3))
  __shared__ f16 h2s[64 * 128];   // 16KB, same swizzle
  const int ci = blockIdx.x;
  const int base = (ci >> 10) << 12;
  const int t = threadIdx.x;
  const int lane = t & 63;
  const int wv = __builtin_amdgcn_readfirstlane((int)(t >> 6));
  const int m = lane & 15, qq = lane >> 4;

  const int j = nbr[(ci << 6) + lane];
  const bool valid = j >= 0;
  const int cnt = __popcll(__ballot(valid));   // valid rows are exactly [0, cnt)
  const int j0 = __shfl(j, 0);
  const int jjn = valid ? j : (j0 >= 0 ? j0 : 0);

  const float qx = qpos[ci * 3 + 0], qy = qpos[ci * 3 + 1], qz = qpos[ci * 3 + 2];
  const float rx = pos[(size_t)(base + jjn) * 3 + 0] - qx;
  const float ry = pos[(size_t)(base + jjn) * 3 + 1] - qy;
  const float rz = pos[(size_t)(base + jjn) * 3 + 2] - qz;

  // ---- phase 1: h1 = relu(P[j] + rel@W1b), cols [wv*32, wv*32+32), lane = row ----
  {
    const f16* Prow = P + (size_t)(base + jjn) * D1;
    const int r = lane;
    #pragma unroll
    for (int c8 = 0; c8 < 4; ++c8) {
      const int c0 = wv * 32 + c8 * 8;
      const half8 pv = *(const half8*)(Prow + c0);
      half8 hv;
      #pragma unroll
      for (int u = 0; u < 8; ++u) {
        const int c = c0 + u;
        float v = (float)pv[u] + rx * W1b[c] + ry * W1b[128 + c] + rz * W1b[256 + c];
        hv[u] = (f16)fmaxf(v, 0.0f);
      }
      *(half8*)(h1s + r * 128 + (c0 ^ ((r & 7) << 3))) = hv;
    }
  }
  __syncthreads();

  // ---- phase 2: h2 = relu(h1 @ W2 + b2), wave computes cols [wv*32, wv*32+32) ----
  {
    floatx4 acc[2][4];
    #pragma unroll
    for (int cs = 0; cs < 2; ++cs)
      #pragma unroll
      for (int rt = 0; rt < 4; ++rt) acc[cs][rt] = floatx4{0.f, 0.f, 0.f, 0.f};
    #pragma unroll
    for (int ks = 0; ks < 4; ++ks) {
      const int kk = ks * 32 + qq * 8;
      half8 af[4];
      #pragma unroll
      for (int rt = 0; rt < 4; ++rt) {
        const int r = rt * 16 + m;
        af[rt] = *(const half8*)(h1s + r * 128 + (kk ^ ((r & 7) << 3)));
      }
      half8 bf[2];
      #pragma unroll
      for (int cs = 0; cs < 2; ++cs) {
        const int c = (wv * 2 + cs) * 16 + m;
        bf[cs] = *(const half8*)(W2t + (size_t)c * 128 + kk);
      }
      #pragma unroll
      for (int cs = 0; cs < 2; ++cs)
        #pragma unroll
        for (int rt = 0; rt < 4; ++rt)
          acc[cs][rt] = __builtin_amdgcn_mfma_f32_16x16x32_f16(af[rt], bf[cs], acc[cs][rt], 0, 0, 0);
    }
    #pragma unroll
    for (int cs = 0; cs < 2; ++cs) {
      const int c = (wv * 2 + cs) * 16 + m;
      const float bias = b2c[c];
      #pragma unroll
      for (int rt = 0; rt < 4; ++rt) {
        #pragma unroll
        for (int u = 0; u < 4; ++u) {
          const int r = rt * 16 + qq * 4 + u;   // C layout: col=lane&15, row=(lane>>4)*4+u
          h2s[r * 128 + (c ^ ((r & 7) << 3))] = (f16)fmaxf(acc[cs][rt][u] + bias, 0.0f);
        }
      }
    }
  }
  __syncthreads();

  // ---- phase 3: h3 = relu(h2 @ W3 + b3); masked max over rows; wave cols [wv*64,+64) ----
  {
    floatx4 acc[4][4];
    #pragma unroll
    for (int ct = 0; ct < 4; ++ct)
      #pragma unroll
      for (int rt = 0; rt < 4; ++rt) acc[ct][rt] = floatx4{0.f, 0.f, 0.f, 0.f};
    #pragma unroll
    for (int ks = 0; ks < 4; ++ks) {
      const int kk = ks * 32 + qq * 8;
      half8 af[4];
      #pragma unroll
      for (int rt = 0; rt < 4; ++rt) {
        const int r = rt * 16 + m;
        af[rt] = *(const half8*)(h2s + r * 128 + (kk ^ ((r & 7) << 3)));
      }
      half8 bf[4];
      #pragma unroll
      for (int ct = 0; ct < 4; ++ct) {
        const int c = (wv * 4 + ct) * 16 + m;
        bf[ct] = *(const half8*)(W3t + (size_t)c * 128 + kk);
      }
      #pragma unroll
      for (int ct = 0; ct < 4; ++ct)
        #pragma unroll
        for (int rt = 0; rt < 4; ++rt)
          acc[ct][rt] = __builtin_amdgcn_mfma_f32_16x16x32_f16(af[rt], bf[ct], acc[ct][rt], 0, 0, 0);
    }
    #pragma unroll
    for (int ct = 0; ct < 4; ++ct) {
      const int c = (wv * 4 + ct) * 16 + m;
      const float bias = b3c[c];
      float mx = -INFINITY;
      #pragma unroll
      for (int rt = 0; rt < 4; ++rt) {
        #pragma unroll
        for (int u = 0; u < 4; ++u) {
          const int r = rt * 16 + qq * 4 + u;
          float v = fmaxf(acc[ct][rt][u] + bias, 0.0f);
          v = (r < cnt) ? v : -INFINITY;
          mx = fmaxf(mx, v);
        }
      }
      mx = fmaxf(mx, __shfl_xor(mx, 16));
      mx = fmaxf(mx, __shfl_xor(mx, 32));
      mx = (cnt > 0) ? mx : 0.0f;
      if (qq == 0) out[(size_t)ci * D3 + c] = mx;
    }
  }
}

extern "C" void kernel_launch(void* const* d_in, const int* in_sizes, int n_in,
                              void* d_out, int out_size, void* d_ws, size_t ws_size,
                              hipStream_t stream) {
  const float* x   = (const float*)d_in[0];
  const float* pos = (const float*)d_in[1];
  // d_in[2] = batch: layout known (sorted, NP per cloud) -> unused
  const float* W1 = (const float*)d_in[3];
  const float* b1 = (const float*)d_in[4];
  const float* W2 = (const float*)d_in[5];
  const float* b2 = (const float*)d_in[6];
  const float* W3 = (const float*)d_in[7];
  const float* b3 = (const float*)d_in[8];
  float* out = (float*)d_out;

  char* ws = (char*)d_ws;
  f16*   P    = (f16*)  (ws + 0);          // 8,388,608 B
  float* qpos = (float*)(ws + 8388608);    //    98,304 B
  int*   nbr  = (int*)  (ws + 8486912);    // 2,097,152 B
  f16*   W2t  = (f16*)  (ws + 10584064);   //    32,768 B
  f16*   W3t  = (f16*)  (ws + 10616832);   //    65,536 B
  float* W1b  = (float*)(ws + 10682368);   //     1,536 B   (total ~10.2 MB)

  front_kernel<<<NB / 2 + 1024 + 64, 256, sizeof(FpsS2), stream>>>(
      pos, x, W1, b1, W2, W3, qpos, P, W2t, W3t, W1b, out);
  ballq_kernel<<<NC / 4, 256, 0, stream>>>(pos, qpos, nbr);
  mlp_kernel<<<NC, 256, 0, stream>>>(pos, qpos, nbr, P, W1b, W2t, b2, W3t, b3, out);
}

// Round 11
// 912.038 us; speedup vs baseline: 1.3483x; 1.3483x over previous
//
#include <hip/hip_runtime.h>

// PointNet++ SA module on MI355X.
// Pipeline: fused{cvt, pk, FPS} ; ball query ; fused MLP+max.
// Layer1 trick: x_j@W1a precomputed per point (16x reuse); pair-wise part is only rel@W1b.
// Layers 2/3 use v_mfma_f32_16x16x32_f16 (no fp32 MFMA on CDNA4).
// R8: fuse {fps | pk | cvt} on disjoint blockIdx ranges; ballq 4-wave+barriers (tail 275us).
// R9: packed f32x2 sub/mul/add + scalar min/max in fps update: front 585->531. PROVEN.
// R10: REGRESSED (front 923): 2-clouds-in-one-wave interleave — compiler kept VGPR at 84,
//      i.e. refetched 2x state from LDS per step instead of giving ILP. Zero-barrier ballq
//      also ~neutral vs R8 (307 vs 275 tail). Both reverted.
// R11: latency overlap via HARDWARE wave interleave instead: fps 8 waves (512thr, 2/SIMD),
//      8 pts/lane — same per-SIMD issue, wave B's VALU hides wave A's serial chain
//      (centroid read, DPP ladder, barrier). Merge = 8 keys. pk/cvt adapted to 512 thr.

#define NB 8
#define NP 4096
#define MP 1024
#define NC 8192         // NB*MP centroids
#define CIN 64
#define D1 128
#define D2 128
#define D3 256
#define CAP 512         // ball-query candidate capacity (E[count]~137, 32 sigma safe)

static constexpr float R2F = 0.04f;   // (0.2)^2 in f32, bit-identical to jnp promotion

typedef _Float16 f16;
typedef _Float16 half8 __attribute__((ext_vector_type(8)));
typedef float floatx4 __attribute__((ext_vector_type(4)));
typedef float f32x2 __attribute__((ext_vector_type(2)));
typedef unsigned long long u64;

// d_out layout (floats): [NC*256 out][NC*3 pos_out][NC batch_out]
#define OUT1 ((size_t)NC * D3)
#define OUT2 (OUT1 + (size_t)NC * 3)

// -------- fused front end: blocks 0-7 FPS, 8-1031 pk, 1032-1095 cvt (512 thr) --------
template<int CTRL>
__device__ __forceinline__ float dppmax(float v) {
  const int iv = __builtin_bit_cast(int, v);
  const int sh = __builtin_amdgcn_update_dpp(iv, iv, CTRL, 0xf, 0xf, false);
  return fmaxf(v, __builtin_bit_cast(float, sh));
}

struct FpsS { float ldspos[NP * 3]; u64 pkey[2][8]; int cidx[MP]; };   // 53,376 B
struct PkS  { float wl[CIN * D1]; float xl[32 * CIN]; };               // 40,960 B

__launch_bounds__(512)
__global__ void front_kernel(const float* __restrict__ pos, const float* __restrict__ x,
                             const float* __restrict__ W1, const float* __restrict__ b1,
                             const float* __restrict__ W2, const float* __restrict__ W3,
                             float* __restrict__ qpos, f16* __restrict__ P,
                             f16* __restrict__ W2t, f16* __restrict__ W3t,
                             float* __restrict__ W1b, float* __restrict__ dout) {
  #pragma clang fp contract(off)
  __shared__ __align__(16) char raw[sizeof(FpsS)];
  const int bid = blockIdx.x;
  const int t = threadIdx.x;

  if (bid < NB) {
    // ========= FPS: 1 block (8 waves, 2/SIMD) per cloud — HW latency overlap =========
    FpsS& S = *reinterpret_cast<FpsS*>(raw);
    const int b = bid;
    const int lane = t & 63, wv = t >> 6;
    for (int e = t; e < NP * 3; e += 512) S.ldspos[e] = pos[(size_t)b * NP * 3 + e];
    __syncthreads();
    // blocked mapping: thread t owns points [t*8, t*8+8) -> lane order == index order
    // coords packed f32x2 (v_pk_add/mul_f32); d scalar (no v_pk_min/max on gfx950)
    f32x2 px[4], py[4], pz[4];
    float d[8];
    #pragma unroll
    for (int i = 0; i < 4; ++i) {
      const int p = t * 8 + 2 * i;
      px[i] = (f32x2){S.ldspos[p * 3 + 0], S.ldspos[p * 3 + 3]};
      py[i] = (f32x2){S.ldspos[p * 3 + 1], S.ldspos[p * 3 + 4]};
      pz[i] = (f32x2){S.ldspos[p * 3 + 2], S.ldspos[p * 3 + 5]};
      d[2 * i] = INFINITY; d[2 * i + 1] = INFINITY;
    }
    int g = 0;
    for (int step = 0; step < MP; ++step) {
      if (t == 0) S.cidx[step] = g;
      const float cx = S.ldspos[g * 3 + 0], cy = S.ldspos[g * 3 + 1], cz = S.ldspos[g * 3 + 2];
      const f32x2 cx2 = cx, cy2 = cy, cz2 = cz;
      // packed sub/mul/add (contract off -> separate rn ops, exact JAX order)
      float lv = -1.0f;
      #pragma unroll
      for (int i = 0; i < 4; ++i) {
        const f32x2 dx = px[i] - cx2;
        const f32x2 dy = py[i] - cy2;
        const f32x2 dz = pz[i] - cz2;
        const f32x2 nd = (dx * dx + dy * dy) + dz * dz;
        d[2 * i]     = fminf(d[2 * i],     nd.x);
        d[2 * i + 1] = fminf(d[2 * i + 1], nd.y);
        lv = fmaxf(lv, d[2 * i]);
        lv = fmaxf(lv, d[2 * i + 1]);
      }
      // lane-local argmax, lowest-i tie-break (descending overwrite)
      int li = 7;
      #pragma unroll
      for (int i = 6; i >= 0; --i) li = (d[i] == lv) ? i : li;
      // in-wave max via DPP (VALU pipe): result in lane 63
      float wm = lv;
      wm = dppmax<0xB1>(wm);    // quad_perm [1,0,3,2]
      wm = dppmax<0x4E>(wm);    // quad_perm [2,3,0,1]
      wm = dppmax<0x141>(wm);   // row_half_mirror
      wm = dppmax<0x140>(wm);   // row_mirror
      wm = dppmax<0x142>(wm);   // row_bcast:15
      wm = dppmax<0x143>(wm);   // row_bcast:31
      const float M = __builtin_bit_cast(float,
          __builtin_amdgcn_readlane(__builtin_bit_cast(int, wm), 63));
      // wave argmax: lowest lane holding M, then its lowest i
      const u64 bal = __ballot(lv == M);
      const int Ls = (int)__builtin_ctzll(bal);
      const int sli = __builtin_amdgcn_readlane(li, Ls);
      const int gw = ((wv << 6) + Ls) * 8 + sli;   // wave winner global idx
      if (lane == 0)
        S.pkey[step & 1][wv] = ((u64)__float_as_uint(M) << 32) | (unsigned int)~gw;
      __syncthreads();
      // cross-wave: 8 keys, 7 u64 compare-selects (redundant in every thread)
      u64 best = S.pkey[step & 1][0];
      #pragma unroll
      for (int w = 1; w < 8; ++w) {
        const u64 o = S.pkey[step & 1][w];
        best = o > best ? o : best;
      }
      g = (int)~(unsigned int)best;
    }
    __syncthreads();
    // epilogue: flush all centroid outputs in parallel
    for (int s = t; s < MP; s += 512) {
      const int ci = (b << 10) + s;
      const int p = S.cidx[s];
      const float cx = S.ldspos[p * 3 + 0], cy = S.ldspos[p * 3 + 1], cz = S.ldspos[p * 3 + 2];
      qpos[ci * 3 + 0] = cx; qpos[ci * 3 + 1] = cy; qpos[ci * 3 + 2] = cz;
      dout[OUT1 + (size_t)ci * 3 + 0] = cx;
      dout[OUT1 + (size_t)ci * 3 + 1] = cy;
      dout[OUT1 + (size_t)ci * 3 + 2] = cz;
      dout[OUT2 + ci] = (float)b;
    }
  } else if (bid < NB + 1024) {
    // ====== pk: P = x @ W1[0:64] + b1 (fp16 out), 32 rows/block, 512 threads =========
    PkS& S = *reinterpret_cast<PkS*>(raw);
    const int r0 = (bid - NB) * 32;
    for (int e = t; e < CIN * D1; e += 512) S.wl[e] = W1[e];
    for (int e = t; e < 32 * CIN; e += 512)
      S.xl[e] = x[(size_t)(r0 + (e >> 6)) * CIN + (e & 63)];
    __syncthreads();
    const int c = t & 127;
    const int rh = t >> 7;           // wave-uniform, 0..3
    const float bc = b1[c];
    for (int rr = 0; rr < 32; rr += 4) {
      const int r = rr + rh;
      float acc = bc;
      #pragma unroll
      for (int k = 0; k < CIN; ++k) acc = __fmaf_rn(S.xl[r * CIN + k], S.wl[k * D1 + c], acc);
      P[(size_t)(r0 + r) * D1 + c] = (f16)acc;
    }
  } else {
    // ========= cvt: weight transpose -> fp16 (64 blocks, grid-stride, 512 thr) ========
    const int stride = 64 * 512;
    const int i = (bid - (NB + 1024)) * 512 + t;
    for (int e = i; e < D1 * D2; e += stride) {      // W2t[c][k] = W2[k][c]
      int c = e >> 7, k = e & 127;
      W2t[c * 128 + k] = (f16)W2[k * D2 + c];
    }
    for (int e = i; e < D2 * D3; e += stride) {      // W3t[c][k] = W3[k][c]
      int c = e >> 7, k = e & 127;
      W3t[c * 128 + k] = (f16)W3[k * D3 + c];
    }
    for (int e = i; e < 3 * D1; e += stride) W1b[e] = W1[64 * D1 + e];  // rel rows of W1
  }
}

// ---------------- ball query (R8 proven form): 4 waves, 1 centroid each ----------------
__launch_bounds__(256)
__global__ void ballq_kernel(const float* __restrict__ pos, const float* __restrict__ qpos,
                             int* __restrict__ nbr) {
  __shared__ unsigned long long list[4][CAP];   // 16KB
  const int t = threadIdx.x;
  const int wv = t >> 6, lane = t & 63;
  const int ci = blockIdx.x * 4 + wv;
  const int b = ci >> 10;
  const int base = b * NP;
  const float qx = qpos[ci * 3 + 0], qy = qpos[ci * 3 + 1], qz = qpos[ci * 3 + 2];
  int cnt = 0;
  for (int chunk = 0; chunk < NP / 64; ++chunk) {
    const int p = chunk * 64 + lane;
    const float x = pos[(size_t)(base + p) * 3 + 0];
    const float y = pos[(size_t)(base + p) * 3 + 1];
    const float z = pos[(size_t)(base + p) * 3 + 2];
    const float dx = __fsub_rn(qx, x), dy = __fsub_rn(qy, y), dz = __fsub_rn(qz, z);
    const float d2 = __fadd_rn(__fadd_rn(__fmul_rn(dx, dx), __fmul_rn(dy, dy)),
                               __fmul_rn(dz, dz));
    const bool in = d2 <= R2F;
    const unsigned long long mask = __ballot(in);
    if (in) {
      const int slot = cnt + __popcll(mask & ((1ull << lane) - 1ull));
      if (slot < CAP)
        list[wv][slot] = ((unsigned long long)__float_as_uint(d2) << 32) | (unsigned int)p;
    }
    cnt += __popcll(mask);
  }
  const int cntc = cnt < CAP ? cnt : CAP;
  for (int s = cntc + lane; s < CAP; s += 64) list[wv][s] = ~0ull;
  __syncthreads();
  // bitonic ascending sort of (d2_bits, idx) -> exact top_k tie-break (lowest idx)
  for (int ks = 2; ks <= CAP; ks <<= 1) {
    for (int jj = ks >> 1; jj > 0; jj >>= 1) {
      for (int i = lane; i < CAP; i += 64) {
        const int partner = i ^ jj;
        if (partner > i) {
          const bool up = ((i & ks) == 0);
          const unsigned long long a = list[wv][i], c = list[wv][partner];
          if (up ? (a > c) : (a < c)) { list[wv][i] = c; list[wv][partner] = a; }
        }
      }
      __syncthreads();
    }
  }
  const unsigned long long e = list[wv][lane];
  const int idx = (int)(e & 0xFFFFFFFFull);
  nbr[(ci << 6) + lane] = (lane < cntc) ? idx : -1;
}

// ---------------- fused MLP + max aggregation: 1 block (4 waves) per centroid ----------------
__launch_bounds__(256)
__global__ void mlp_kernel(const float* __restrict__ pos, const float* __restrict__ qpos,
                           const int* __restrict__ nbr, const f16* __restrict__ P,
                           const float* __restrict__ W1b, const f16* __restrict__ W2t,
                           const float* __restrict__ b2c, const f16* __restrict__ W3t,
                           const float* __restrict__ b3c, float* __restrict__ out) {
  __shared__ f16 h1s[64 * 128];   // 16KB, element (r,k) at r*128 + (k ^ ((r&7)<<3))
  __shared__ f16 h2s[64 * 128];   // 16KB, same swizzle
  const int ci = blockIdx.x;
  const int base = (ci >> 10) << 12;
  const int t = threadIdx.x;
  const int lane = t & 63;
  const int wv = __builtin_amdgcn_readfirstlane((int)(t >> 6));
  const int m = lane & 15, qq = lane >> 4;

  const int j = nbr[(ci << 6) + lane];
  const bool valid = j >= 0;
  const int cnt = __popcll(__ballot(valid));   // valid rows are exactly [0, cnt)
  const int j0 = __shfl(j, 0);
  const int jjn = valid ? j : (j0 >= 0 ? j0 : 0);

  const float qx = qpos[ci * 3 + 0], qy = qpos[ci * 3 + 1], qz = qpos[ci * 3 + 2];
  const float rx = pos[(size_t)(base + jjn) * 3 + 0] - qx;
  const float ry = pos[(size_t)(base + jjn) * 3 + 1] - qy;
  const float rz = pos[(size_t)(base + jjn) * 3 + 2] - qz;

  // ---- phase 1: h1 = relu(P[j] + rel@W1b), cols [wv*32, wv*32+32), lane = row ----
  {
    const f16* Prow = P + (size_t)(base + jjn) * D1;
    const int r = lane;
    #pragma unroll
    for (int c8 = 0; c8 < 4; ++c8) {
      const int c0 = wv * 32 + c8 * 8;
      const half8 pv = *(const half8*)(Prow + c0);
      half8 hv;
      #pragma unroll
      for (int u = 0; u < 8; ++u) {
        const int c = c0 + u;
        float v = (float)pv[u] + rx * W1b[c] + ry * W1b[128 + c] + rz * W1b[256 + c];
        hv[u] = (f16)fmaxf(v, 0.0f);
      }
      *(half8*)(h1s + r * 128 + (c0 ^ ((r & 7) << 3))) = hv;
    }
  }
  __syncthreads();

  // ---- phase 2: h2 = relu(h1 @ W2 + b2), wave computes cols [wv*32, wv*32+32) ----
  {
    floatx4 acc[2][4];
    #pragma unroll
    for (int cs = 0; cs < 2; ++cs)
      #pragma unroll
      for (int rt = 0; rt < 4; ++rt) acc[cs][rt] = floatx4{0.f, 0.f, 0.f, 0.f};
    #pragma unroll
    for (int ks = 0; ks < 4; ++ks) {
      const int kk = ks * 32 + qq * 8;
      half8 af[4];
      #pragma unroll
      for (int rt = 0; rt < 4; ++rt) {
        const int r = rt * 16 + m;
        af[rt] = *(const half8*)(h1s + r * 128 + (kk ^ ((r & 7) << 3)));
      }
      half8 bf[2];
      #pragma unroll
      for (int cs = 0; cs < 2; ++cs) {
        const int c = (wv * 2 + cs) * 16 + m;
        bf[cs] = *(const half8*)(W2t + (size_t)c * 128 + kk);
      }
      #pragma unroll
      for (int cs = 0; cs < 2; ++cs)
        #pragma unroll
        for (int rt = 0; rt < 4; ++rt)
          acc[cs][rt] = __builtin_amdgcn_mfma_f32_16x16x32_f16(af[rt], bf[cs], acc[cs][rt], 0, 0, 0);
    }
    #pragma unroll
    for (int cs = 0; cs < 2; ++cs) {
      const int c = (wv * 2 + cs) * 16 + m;
      const float bias = b2c[c];
      #pragma unroll
      for (int rt = 0; rt < 4; ++rt) {
        #pragma unroll
        for (int u = 0; u < 4; ++u) {
          const int r = rt * 16 + qq * 4 + u;   // C layout: col=lane&15, row=(lane>>4)*4+u
          h2s[r * 128 + (c ^ ((r & 7) << 3))] = (f16)fmaxf(acc[cs][rt][u] + bias, 0.0f);
        }
      }
    }
  }
  __syncthreads();

  // ---- phase 3: h3 = relu(h2 @ W3 + b3); masked max over rows; wave cols [wv*64,+64) ----
  {
    floatx4 acc[4][4];
    #pragma unroll
    for (int ct = 0; ct < 4; ++ct)
      #pragma unroll
      for (int rt = 0; rt < 4; ++rt) acc[ct][rt] = floatx4{0.f, 0.f, 0.f, 0.f};
    #pragma unroll
    for (int ks = 0; ks < 4; ++ks) {
      const int kk = ks * 32 + qq * 8;
      half8 af[4];
      #pragma unroll
      for (int rt = 0; rt < 4; ++rt) {
        const int r = rt * 16 + m;
        af[rt] = *(const half8*)(h2s + r * 128 + (kk ^ ((r & 7) << 3)));
      }
      half8 bf[4];
      #pragma unroll
      for (int ct = 0; ct < 4; ++ct) {
        const int c = (wv * 4 + ct) * 16 + m;
        bf[ct] = *(const half8*)(W3t + (size_t)c * 128 + kk);
      }
      #pragma unroll
      for (int ct = 0; ct < 4; ++ct)
        #pragma unroll
        for (int rt = 0; rt < 4; ++rt)
          acc[ct][rt] = __builtin_amdgcn_mfma_f32_16x16x32_f16(af[rt], bf[ct], acc[ct][rt], 0, 0, 0);
    }
    #pragma unroll
    for (int ct = 0; ct < 4; ++ct) {
      const int c = (wv * 4 + ct) * 16 + m;
      const float bias = b3c[c];
      float mx = -INFINITY;
      #pragma unroll
      for (int rt = 0; rt < 4; ++rt) {
        #pragma unroll
        for (int u = 0; u < 4; ++u) {
          const int r = rt * 16 + qq * 4 + u;
          float v = fmaxf(acc[ct][rt][u] + bias, 0.0f);
          v = (r < cnt) ? v : -INFINITY;
          mx = fmaxf(mx, v);
        }
      }
      mx = fmaxf(mx, __shfl_xor(mx, 16));
      mx = fmaxf(mx, __shfl_xor(mx, 32));
      mx = (cnt > 0) ? mx : 0.0f;
      if (qq == 0) out[(size_t)ci * D3 + c] = mx;
    }
  }
}

extern "C" void kernel_launch(void* const* d_in, const int* in_sizes, int n_in,
                              void* d_out, int out_size, void* d_ws, size_t ws_size,
                              hipStream_t stream) {
  const float* x   = (const float*)d_in[0];
  const float* pos = (const float*)d_in[1];
  // d_in[2] = batch: layout known (sorted, NP per cloud) -> unused
  const float* W1 = (const float*)d_in[3];
  const float* b1 = (const float*)d_in[4];
  const float* W2 = (const float*)d_in[5];
  const float* b2 = (const float*)d_in[6];
  const float* W3 = (const float*)d_in[7];
  const float* b3 = (const float*)d_in[8];
  float* out = (float*)d_out;

  char* ws = (char*)d_ws;
  f16*   P    = (f16*)  (ws + 0);          // 8,388,608 B
  float* qpos = (float*)(ws + 8388608);    //    98,304 B
  int*   nbr  = (int*)  (ws + 8486912);    // 2,097,152 B
  f16*   W2t  = (f16*)  (ws + 10584064);   //    32,768 B
  f16*   W3t  = (f16*)  (ws + 10616832);   //    65,536 B
  float* W1b  = (float*)(ws + 10682368);   //     1,536 B   (total ~10.2 MB)

  front_kernel<<<NB + 1024 + 64, 512, 0, stream>>>(pos, x, W1, b1, W2, W3,
                                                   qpos, P, W2t, W3t, W1b, out);
  ballq_kernel<<<NC / 4, 256, 0, stream>>>(pos, qpos, nbr);
  mlp_kernel<<<NC, 256, 0, stream>>>(pos, qpos, nbr, P, W1b, W2t, b2, W3t, b3, out);
}

// Round 12
// 786.119 us; speedup vs baseline: 1.5643x; 1.1602x over previous
//
#include <hip/hip_runtime.h>

// PointNet++ SA module on MI355X.
// Pipeline: fused{cvt, pk, FPS} ; ball query ; fused MLP+max.
// Layer1 trick: x_j@W1a precomputed per point (16x reuse); pair-wise part is only rel@W1b.
// Layers 2/3 use v_mfma_f32_16x16x32_f16 (no fp32 MFMA on CDNA4).
// R8: fuse {fps | pk | cvt} on disjoint blockIdx ranges; ballq 4-wave+barriers.
// R9: fps packed f32x2 sub/mul/add + scalar min/max: front 585->531. PROVEN BEST.
// R10: REGRESSED: 2-clouds-per-wave (VGPR stayed 84 -> LDS refetch, front 923).
// R11: REGRESSED: 8-wave fps (front 617) — barrier syncs more waves, overlap never
//      materializes (both waves stall at the same barrier). fps ~531 is this
//      structure's serial-latency floor. Reverted to R9 front.
// R12: ballq dynamic sort size SS in {256,512}: cnt ~ 137+-12, so sort 256 (36 passes,
//      4 elems/lane) instead of always-512 (45 passes, 8 elems/lane) = 2.5x fewer
//      element-ops. SS is BLOCK-uniform (max over 4 waves) so all waves execute the
//      same barrier count (no barrier divergence).

#define NB 8
#define NP 4096
#define MP 1024
#define NC 8192         // NB*MP centroids
#define CIN 64
#define D1 128
#define D2 128
#define D3 256
#define CAP 512         // ball-query candidate capacity (E[count]~137, 32 sigma safe)

static constexpr float R2F = 0.04f;   // (0.2)^2 in f32, bit-identical to jnp promotion

typedef _Float16 f16;
typedef _Float16 half8 __attribute__((ext_vector_type(8)));
typedef float floatx4 __attribute__((ext_vector_type(4)));
typedef float f32x2 __attribute__((ext_vector_type(2)));
typedef unsigned long long u64;

// d_out layout (floats): [NC*256 out][NC*3 pos_out][NC batch_out]
#define OUT1 ((size_t)NC * D3)
#define OUT2 (OUT1 + (size_t)NC * 3)

// ---------------- fused front end: blocks 0-7 FPS, 8-1031 pk, 1032-1095 cvt ----------
template<int CTRL>
__device__ __forceinline__ float dppmax(float v) {
  const int iv = __builtin_bit_cast(int, v);
  const int sh = __builtin_amdgcn_update_dpp(iv, iv, CTRL, 0xf, 0xf, false);
  return fmaxf(v, __builtin_bit_cast(float, sh));
}

struct FpsS { float ldspos[NP * 3]; u64 pkey[2][4]; int cidx[MP]; };   // 53,312 B
struct PkS  { float wl[CIN * D1]; float xl[32 * CIN]; };               // 40,960 B

__launch_bounds__(256)
__global__ void front_kernel(const float* __restrict__ pos, const float* __restrict__ x,
                             const float* __restrict__ W1, const float* __restrict__ b1,
                             const float* __restrict__ W2, const float* __restrict__ W3,
                             float* __restrict__ qpos, f16* __restrict__ P,
                             f16* __restrict__ W2t, f16* __restrict__ W3t,
                             float* __restrict__ W1b, float* __restrict__ dout) {
  #pragma clang fp contract(off)
  __shared__ __align__(16) char raw[sizeof(FpsS)];
  const int bid = blockIdx.x;
  const int t = threadIdx.x;

  if (bid < NB) {
    // ================= FPS: 1 block (4 waves, 1/SIMD) per cloud =================
    FpsS& S = *reinterpret_cast<FpsS*>(raw);
    const int b = bid;
    const int lane = t & 63, wv = t >> 6;
    for (int e = t; e < NP * 3; e += 256) S.ldspos[e] = pos[(size_t)b * NP * 3 + e];
    __syncthreads();
    // blocked mapping: thread t owns points [t*16, t*16+16) -> lane order == index order
    // coords packed f32x2 (v_pk_add/mul_f32); d scalar (no v_pk_min/max on gfx950)
    f32x2 px[8], py[8], pz[8];
    float d[16];
    #pragma unroll
    for (int i = 0; i < 8; ++i) {
      const int p = t * 16 + 2 * i;
      px[i] = (f32x2){S.ldspos[p * 3 + 0], S.ldspos[p * 3 + 3]};
      py[i] = (f32x2){S.ldspos[p * 3 + 1], S.ldspos[p * 3 + 4]};
      pz[i] = (f32x2){S.ldspos[p * 3 + 2], S.ldspos[p * 3 + 5]};
      d[2 * i] = INFINITY; d[2 * i + 1] = INFINITY;
    }
    int g = 0;
    for (int step = 0; step < MP; ++step) {
      if (t == 0) S.cidx[step] = g;
      const float cx = S.ldspos[g * 3 + 0], cy = S.ldspos[g * 3 + 1], cz = S.ldspos[g * 3 + 2];
      const f32x2 cx2 = cx, cy2 = cy, cz2 = cz;
      // packed sub/mul/add (contract off -> separate rn ops, exact JAX order)
      float lv = -1.0f;
      #pragma unroll
      for (int i = 0; i < 8; ++i) {
        const f32x2 dx = px[i] - cx2;
        const f32x2 dy = py[i] - cy2;
        const f32x2 dz = pz[i] - cz2;
        const f32x2 nd = (dx * dx + dy * dy) + dz * dz;
        d[2 * i]     = fminf(d[2 * i],     nd.x);
        d[2 * i + 1] = fminf(d[2 * i + 1], nd.y);
        lv = fmaxf(lv, d[2 * i]);
        lv = fmaxf(lv, d[2 * i + 1]);
      }
      // lane-local argmax, lowest-i tie-break (descending overwrite)
      int li = 15;
      #pragma unroll
      for (int i = 14; i >= 0; --i) li = (d[i] == lv) ? i : li;
      // in-wave max via DPP (VALU pipe): result in lane 63
      float wm = lv;
      wm = dppmax<0xB1>(wm);    // quad_perm [1,0,3,2]
      wm = dppmax<0x4E>(wm);    // quad_perm [2,3,0,1]
      wm = dppmax<0x141>(wm);   // row_half_mirror
      wm = dppmax<0x140>(wm);   // row_mirror
      wm = dppmax<0x142>(wm);   // row_bcast:15
      wm = dppmax<0x143>(wm);   // row_bcast:31
      const float M = __builtin_bit_cast(float,
          __builtin_amdgcn_readlane(__builtin_bit_cast(int, wm), 63));
      // wave argmax: lowest lane holding M, then its lowest i
      const u64 bal = __ballot(lv == M);
      const int Ls = (int)__builtin_ctzll(bal);
      const int sli = __builtin_amdgcn_readlane(li, Ls);
      const int gw = ((wv << 6) + Ls) * 16 + sli;   // wave winner global idx
      if (lane == 0)
        S.pkey[step & 1][wv] = ((u64)__float_as_uint(M) << 32) | (unsigned int)~gw;
      __syncthreads();
      // cross-wave: 4 keys, 3 u64 compare-selects (redundant in every thread)
      u64 best = S.pkey[step & 1][0];
      #pragma unroll
      for (int w = 1; w < 4; ++w) {
        const u64 o = S.pkey[step & 1][w];
        best = o > best ? o : best;
      }
      g = (int)~(unsigned int)best;
    }
    __syncthreads();
    // epilogue: flush all centroid outputs in parallel
    for (int s = t; s < MP; s += 256) {
      const int ci = (b << 10) + s;
      const int p = S.cidx[s];
      const float cx = S.ldspos[p * 3 + 0], cy = S.ldspos[p * 3 + 1], cz = S.ldspos[p * 3 + 2];
      qpos[ci * 3 + 0] = cx; qpos[ci * 3 + 1] = cy; qpos[ci * 3 + 2] = cz;
      dout[OUT1 + (size_t)ci * 3 + 0] = cx;
      dout[OUT1 + (size_t)ci * 3 + 1] = cy;
      dout[OUT1 + (size_t)ci * 3 + 2] = cz;
      dout[OUT2 + ci] = (float)b;
    }
  } else if (bid < NB + 1024) {
    // ================= pk: P = x @ W1[0:64] + b1 (fp16 out), 32 rows/block ==========
    PkS& S = *reinterpret_cast<PkS*>(raw);
    const int r0 = (bid - NB) * 32;
    for (int e = t; e < CIN * D1; e += 256) S.wl[e] = W1[e];
    for (int e = t; e < 32 * CIN; e += 256)
      S.xl[e] = x[(size_t)(r0 + (e >> 6)) * CIN + (e & 63)];
    __syncthreads();
    const int c = t & 127;
    const int rh = t >> 7;           // wave-uniform (waves 0,1 -> 0; waves 2,3 -> 1)
    const float bc = b1[c];
    for (int rr = 0; rr < 32; rr += 2) {
      const int r = rr + rh;
      float acc = bc;
      #pragma unroll
      for (int k = 0; k < CIN; ++k) acc = __fmaf_rn(S.xl[r * CIN + k], S.wl[k * D1 + c], acc);
      P[(size_t)(r0 + r) * D1 + c] = (f16)acc;
    }
  } else {
    // ================= cvt: weight transpose -> fp16 (64 blocks, grid-stride) ========
    const int stride = 64 * 256;
    const int i = (bid - (NB + 1024)) * 256 + t;
    for (int e = i; e < D1 * D2; e += stride) {      // W2t[c][k] = W2[k][c]
      int c = e >> 7, k = e & 127;
      W2t[c * 128 + k] = (f16)W2[k * D2 + c];
    }
    for (int e = i; e < D2 * D3; e += stride) {      // W3t[c][k] = W3[k][c]
      int c = e >> 7, k = e & 127;
      W3t[c * 128 + k] = (f16)W3[k * D3 + c];
    }
    for (int e = i; e < 3 * D1; e += stride) W1b[e] = W1[64 * D1 + e];  // rel rows of W1
  }
}

// ------ ball query: 4 waves, 1 centroid each; dynamic sort size SS in {256,512} ------
__launch_bounds__(256)
__global__ void ballq_kernel(const float* __restrict__ pos, const float* __restrict__ qpos,
                             int* __restrict__ nbr) {
  __shared__ unsigned long long list[4][CAP];   // 16KB
  __shared__ int cntS[4];
  const int t = threadIdx.x;
  const int wv = t >> 6, lane = t & 63;
  const int ci = blockIdx.x * 4 + wv;
  const int b = ci >> 10;
  const int base = b * NP;
  const float qx = qpos[ci * 3 + 0], qy = qpos[ci * 3 + 1], qz = qpos[ci * 3 + 2];
  int cnt = 0;
  for (int chunk = 0; chunk < NP / 64; ++chunk) {
    const int p = chunk * 64 + lane;
    const float x = pos[(size_t)(base + p) * 3 + 0];
    const float y = pos[(size_t)(base + p) * 3 + 1];
    const float z = pos[(size_t)(base + p) * 3 + 2];
    const float dx = __fsub_rn(qx, x), dy = __fsub_rn(qy, y), dz = __fsub_rn(qz, z);
    const float d2 = __fadd_rn(__fadd_rn(__fmul_rn(dx, dx), __fmul_rn(dy, dy)),
                               __fmul_rn(dz, dz));
    const bool in = d2 <= R2F;
    const unsigned long long mask = __ballot(in);
    if (in) {
      const int slot = cnt + __popcll(mask & ((1ull << lane) - 1ull));
      if (slot < CAP)
        list[wv][slot] = ((unsigned long long)__float_as_uint(d2) << 32) | (unsigned int)p;
    }
    cnt += __popcll(mask);
  }
  const int cntc = cnt < CAP ? cnt : CAP;
  if (lane == 0) cntS[wv] = cntc;
  __syncthreads();
  // block-uniform sort size: 256 covers cnt<=256 (mean 137, +10 sigma); else 512.
  const int cmax = max(max(cntS[0], cntS[1]), max(cntS[2], cntS[3]));
  const int SS = (cmax <= 256) ? 256 : 512;
  for (int s = cntc + lane; s < SS; s += 64) list[wv][s] = ~0ull;
  __syncthreads();
  // bitonic ascending sort of (d2_bits, idx) -> exact top_k tie-break (lowest idx)
  for (int ks = 2; ks <= SS; ks <<= 1) {
    for (int jj = ks >> 1; jj > 0; jj >>= 1) {
      for (int i = lane; i < SS; i += 64) {
        const int partner = i ^ jj;
        if (partner > i) {
          const bool up = ((i & ks) == 0);
          const unsigned long long a = list[wv][i], c = list[wv][partner];
          if (up ? (a > c) : (a < c)) { list[wv][i] = c; list[wv][partner] = a; }
        }
      }
      __syncthreads();
    }
  }
  const unsigned long long e = list[wv][lane];
  const int idx = (int)(e & 0xFFFFFFFFull);
  nbr[(ci << 6) + lane] = (lane < cntc) ? idx : -1;
}

// ---------------- fused MLP + max aggregation: 1 block (4 waves) per centroid ----------------
__launch_bounds__(256)
__global__ void mlp_kernel(const float* __restrict__ pos, const float* __restrict__ qpos,
                           const int* __restrict__ nbr, const f16* __restrict__ P,
                           const float* __restrict__ W1b, const f16* __restrict__ W2t,
                           const float* __restrict__ b2c, const f16* __restrict__ W3t,
                           const float* __restrict__ b3c, float* __restrict__ out) {
  __shared__ f16 h1s[64 * 128];   // 16KB, element (r,k) at r*128 + (k ^ ((r&7)<<3))
  __shared__ f16 h2s[64 * 128];   // 16KB, same swizzle
  const int ci = blockIdx.x;
  const int base = (ci >> 10) << 12;
  const int t = threadIdx.x;
  const int lane = t & 63;
  const int wv = __builtin_amdgcn_readfirstlane((int)(t >> 6));
  const int m = lane & 15, qq = lane >> 4;

  const int j = nbr[(ci << 6) + lane];
  const bool valid = j >= 0;
  const int cnt = __popcll(__ballot(valid));   // valid rows are exactly [0, cnt)
  const int j0 = __shfl(j, 0);
  const int jjn = valid ? j : (j0 >= 0 ? j0 : 0);

  const float qx = qpos[ci * 3 + 0], qy = qpos[ci * 3 + 1], qz = qpos[ci * 3 + 2];
  const float rx = pos[(size_t)(base + jjn) * 3 + 0] - qx;
  const float ry = pos[(size_t)(base + jjn) * 3 + 1] - qy;
  const float rz = pos[(size_t)(base + jjn) * 3 + 2] - qz;

  // ---- phase 1: h1 = relu(P[j] + rel@W1b), cols [wv*32, wv*32+32), lane = row ----
  {
    const f16* Prow = P + (size_t)(base + jjn) * D1;
    const int r = lane;
    #pragma unroll
    for (int c8 = 0; c8 < 4; ++c8) {
      const int c0 = wv * 32 + c8 * 8;
      const half8 pv = *(const half8*)(Prow + c0);
      half8 hv;
      #pragma unroll
      for (int u = 0; u < 8; ++u) {
        const int c = c0 + u;
        float v = (float)pv[u] + rx * W1b[c] + ry * W1b[128 + c] + rz * W1b[256 + c];
        hv[u] = (f16)fmaxf(v, 0.0f);
      }
      *(half8*)(h1s + r * 128 + (c0 ^ ((r & 7) << 3))) = hv;
    }
  }
  __syncthreads();

  // ---- phase 2: h2 = relu(h1 @ W2 + b2), wave computes cols [wv*32, wv*32+32) ----
  {
    floatx4 acc[2][4];
    #pragma unroll
    for (int cs = 0; cs < 2; ++cs)
      #pragma unroll
      for (int rt = 0; rt < 4; ++rt) acc[cs][rt] = floatx4{0.f, 0.f, 0.f, 0.f};
    #pragma unroll
    for (int ks = 0; ks < 4; ++ks) {
      const int kk = ks * 32 + qq * 8;
      half8 af[4];
      #pragma unroll
      for (int rt = 0; rt < 4; ++rt) {
        const int r = rt * 16 + m;
        af[rt] = *(const half8*)(h1s + r * 128 + (kk ^ ((r & 7) << 3)));
      }
      half8 bf[2];
      #pragma unroll
      for (int cs = 0; cs < 2; ++cs) {
        const int c = (wv * 2 + cs) * 16 + m;
        bf[cs] = *(const half8*)(W2t + (size_t)c * 128 + kk);
      }
      #pragma unroll
      for (int cs = 0; cs < 2; ++cs)
        #pragma unroll
        for (int rt = 0; rt < 4; ++rt)
          acc[cs][rt] = __builtin_amdgcn_mfma_f32_16x16x32_f16(af[rt], bf[cs], acc[cs][rt], 0, 0, 0);
    }
    #pragma unroll
    for (int cs = 0; cs < 2; ++cs) {
      const int c = (wv * 2 + cs) * 16 + m;
      const float bias = b2c[c];
      #pragma unroll
      for (int rt = 0; rt < 4; ++rt) {
        #pragma unroll
        for (int u = 0; u < 4; ++u) {
          const int r = rt * 16 + qq * 4 + u;   // C layout: col=lane&15, row=(lane>>4)*4+u
          h2s[r * 128 + (c ^ ((r & 7) << 3))] = (f16)fmaxf(acc[cs][rt][u] + bias, 0.0f);
        }
      }
    }
  }
  __syncthreads();

  // ---- phase 3: h3 = relu(h2 @ W3 + b3); masked max over rows; wave cols [wv*64,+64) ----
  {
    floatx4 acc[4][4];
    #pragma unroll
    for (int ct = 0; ct < 4; ++ct)
      #pragma unroll
      for (int rt = 0; rt < 4; ++rt) acc[ct][rt] = floatx4{0.f, 0.f, 0.f, 0.f};
    #pragma unroll
    for (int ks = 0; ks < 4; ++ks) {
      const int kk = ks * 32 + qq * 8;
      half8 af[4];
      #pragma unroll
      for (int rt = 0; rt < 4; ++rt) {
        const int r = rt * 16 + m;
        af[rt] = *(const half8*)(h2s + r * 128 + (kk ^ ((r & 7) << 3)));
      }
      half8 bf[4];
      #pragma unroll
      for (int ct = 0; ct < 4; ++ct) {
        const int c = (wv * 4 + ct) * 16 + m;
        bf[ct] = *(const half8*)(W3t + (size_t)c * 128 + kk);
      }
      #pragma unroll
      for (int ct = 0; ct < 4; ++ct)
        #pragma unroll
        for (int rt = 0; rt < 4; ++rt)
          acc[ct][rt] = __builtin_amdgcn_mfma_f32_16x16x32_f16(af[rt], bf[ct], acc[ct][rt], 0, 0, 0);
    }
    #pragma unroll
    for (int ct = 0; ct < 4; ++ct) {
      const int c = (wv * 4 + ct) * 16 + m;
      const float bias = b3c[c];
      float mx = -INFINITY;
      #pragma unroll
      for (int rt = 0; rt < 4; ++rt) {
        #pragma unroll
        for (int u = 0; u < 4; ++u) {
          const int r = rt * 16 + qq * 4 + u;
          float v = fmaxf(acc[ct][rt][u] + bias, 0.0f);
          v = (r < cnt) ? v : -INFINITY;
          mx = fmaxf(mx, v);
        }
      }
      mx = fmaxf(mx, __shfl_xor(mx, 16));
      mx = fmaxf(mx, __shfl_xor(mx, 32));
      mx = (cnt > 0) ? mx : 0.0f;
      if (qq == 0) out[(size_t)ci * D3 + c] = mx;
    }
  }
}

extern "C" void kernel_launch(void* const* d_in, const int* in_sizes, int n_in,
                              void* d_out, int out_size, void* d_ws, size_t ws_size,
                              hipStream_t stream) {
  const float* x   = (const float*)d_in[0];
  const float* pos = (const float*)d_in[1];
  // d_in[2] = batch: layout known (sorted, NP per cloud) -> unused
  const float* W1 = (const float*)d_in[3];
  const float* b1 = (const float*)d_in[4];
  const float* W2 = (const float*)d_in[5];
  const float* b2 = (const float*)d_in[6];
  const float* W3 = (const float*)d_in[7];
  const float* b3 = (const float*)d_in[8];
  float* out = (float*)d_out;

  char* ws = (char*)d_ws;
  f16*   P    = (f16*)  (ws + 0);          // 8,388,608 B
  float* qpos = (float*)(ws + 8388608);    //    98,304 B
  int*   nbr  = (int*)  (ws + 8486912);    // 2,097,152 B
  f16*   W2t  = (f16*)  (ws + 10584064);   //    32,768 B
  f16*   W3t  = (f16*)  (ws + 10616832);   //    65,536 B
  float* W1b  = (float*)(ws + 10682368);   //     1,536 B   (total ~10.2 MB)

  front_kernel<<<NB + 1024 + 64, 256, 0, stream>>>(pos, x, W1, b1, W2, W3,
                                                   qpos, P, W2t, W3t, W1b, out);
  ballq_kernel<<<NC / 4, 256, 0, stream>>>(pos, qpos, nbr);
  mlp_kernel<<<NC, 256, 0, stream>>>(pos, qpos, nbr, P, W1b, W2t, b2, W3t, b3, out);
}